// Round 3
// baseline (453.420 us; speedup 1.0000x reference)
//
#include <hip/hip_runtime.h>
#include <math.h>

#define NN 50000
#define DD 128
#define NCLS 40
#define EPSV 1e-8f

__device__ __forceinline__ float waveReduceSum(float v) {
    for (int off = 32; off > 0; off >>= 1) v += __shfl_xor(v, off, 64);
    return v;
}

// ---------------- CSR build ----------------

__global__ void hist_kernel(const int* __restrict__ erow, int* __restrict__ cnt, int E) {
    for (int e = blockIdx.x * blockDim.x + threadIdx.x; e < E; e += gridDim.x * blockDim.x)
        atomicAdd(&cnt[erow[e]], 1);
}

__global__ void scan1_kernel(const int* __restrict__ cnt, int* __restrict__ rs,
                             int* __restrict__ bsum, int n) {
    __shared__ int sdata[256];
    int tid = threadIdx.x;
    int gid = blockIdx.x * 256 + tid;
    int v = (gid < n) ? cnt[gid] : 0;
    sdata[tid] = v;
    __syncthreads();
    for (int off = 1; off < 256; off <<= 1) {
        int t = (tid >= off) ? sdata[tid - off] : 0;
        __syncthreads();
        sdata[tid] += t;
        __syncthreads();
    }
    if (gid < n) rs[gid] = sdata[tid] - v;
    if (tid == 255) bsum[blockIdx.x] = sdata[255];
}

__global__ void scan2_kernel(int* __restrict__ bsum, int nb) {
    __shared__ int sdata[256];
    int tid = threadIdx.x;
    int v = (tid < nb) ? bsum[tid] : 0;
    sdata[tid] = v;
    __syncthreads();
    for (int off = 1; off < 256; off <<= 1) {
        int t = (tid >= off) ? sdata[tid - off] : 0;
        __syncthreads();
        sdata[tid] += t;
        __syncthreads();
    }
    if (tid < nb) bsum[tid] = sdata[tid] - v;
}

__global__ void scan3_kernel(int* __restrict__ rs, const int* __restrict__ bsum, int n, int E) {
    int gid = blockIdx.x * 256 + threadIdx.x;
    if (gid < n) rs[gid] += bsum[blockIdx.x];
    else if (gid == n) rs[n] = E;
}

__global__ void fill_kernel(const int* __restrict__ erow, const int* __restrict__ ecol,
                            const float* __restrict__ ew, int* __restrict__ pos,
                            int* __restrict__ ecol_s, float* __restrict__ ew_s, int E) {
    for (int e = blockIdx.x * blockDim.x + threadIdx.x; e < E; e += gridDim.x * blockDim.x) {
        int r = erow[e];
        int p = atomicAdd(&pos[r], 1);
        ecol_s[p] = ecol[e];
        ew_s[p] = ew[e];
    }
}

// ---------------- fused linears (8 rows per wave) ----------------
// PREEXP=1: X is node_feat (N,127); apply expmap0 first.
// PREEXP=0: X is (N,128) raw agg sums; lorentz-normalize + relu first.
#define RPW 8
template <int PREEXP>
__global__ __launch_bounds__(256, 2) void linear_lorentz(
    const float* __restrict__ X, const float* __restrict__ W,
    const float* __restrict__ bias, const float* __restrict__ logs,
    float* __restrict__ out, int n)
{
    __shared__ float Wt[128 * 128];          // Wt[k][i] = W[i][k]  (64 KB)
    __shared__ float xrow[4][RPW][128];      // 16 KB -> total 80 KB = 2 blocks/CU
    int tid = threadIdx.x;
    for (int idx = tid; idx < 128 * 128; idx += 256) {
        int i = idx >> 7, k = idx & 127;
        Wt[k * 128 + i] = W[idx];
    }
    __syncthreads();
    int wid = tid >> 6, lane = tid & 63;
    float2 bv = *(const float2*)(bias + 2 * lane);     // bias in regs (L2/L1)
    float sval = fminf(expf(logs[0]), 10.f);
    float* xr = &xrow[wid][0][0];
    int nslabs = (n + RPW - 1) / RPW;
    for (int slab = blockIdx.x * 4 + wid; slab < nslabs; slab += gridDim.x * 4) {
        int row0 = slab * RPW;
        // ---- preprocess 8 rows into LDS ----
        #pragma unroll
        for (int r = 0; r < RPW; ++r) {
            int row = row0 + r;
            if (row >= n) { // pad rows: zero (keeps acc finite)
                *(float2*)(xr + r * 128 + 2 * lane) = make_float2(0.f, 0.f);
                continue;
            }
            if (PREEXP) {
                const float* src = X + (long)row * 127;
                float u0 = src[2 * lane];
                float u1 = (2 * lane + 1 < 127) ? src[2 * lane + 1] : 0.f;
                float ss = waveReduceSum(u0 * u0 + u1 * u1);
                float nrm = fmaxf(sqrtf(ss), EPSV);
                float ex = expf(nrm), exn = 1.f / ex;
                float ch = 0.5f * (ex + exn);
                float coef = (0.5f * (ex - exn)) / nrm;
                if (lane == 0) xr[r * 128] = ch;
                xr[r * 128 + 1 + 2 * lane] = coef * u0;
                if (2 * lane + 1 < 127) xr[r * 128 + 2 + 2 * lane] = coef * u1;
            } else {
                float2 e = *(const float2*)(X + (long)row * 128 + 2 * lane);
                float t0 = __shfl(e.x, 0, 64);
                float ss = waveReduceSum(e.x * e.x + e.y * e.y);
                float neg_inner = 2.f * t0 * t0 - ss;
                float inv = 1.f / sqrtf(fmaxf(fabsf(neg_inner), EPSV));
                e.x = fmaxf(e.x * inv, 0.f);
                e.y = fmaxf(e.y * inv, 0.f);
                *(float2*)(xr + r * 128 + 2 * lane) = e;
            }
        }
        // xrow is wave-private: lgkmcnt ordering within wave, no barrier
        // ---- GEMM: 8 rows x 128 cols, W read once per wave ----
        float2 acc[RPW];
        #pragma unroll
        for (int r = 0; r < RPW; ++r) acc[r] = make_float2(0.f, 0.f);
        #pragma unroll 4
        for (int k0 = 0; k0 < 128; k0 += 4) {
            float2 w0 = *(const float2*)(Wt + (k0 + 0) * 128 + 2 * lane);
            float2 w1 = *(const float2*)(Wt + (k0 + 1) * 128 + 2 * lane);
            float2 w2 = *(const float2*)(Wt + (k0 + 2) * 128 + 2 * lane);
            float2 w3 = *(const float2*)(Wt + (k0 + 3) * 128 + 2 * lane);
            #pragma unroll
            for (int r = 0; r < RPW; ++r) {
                float4 xq = *(const float4*)(xr + r * 128 + k0);   // broadcast read
                acc[r].x = fmaf(xq.x, w0.x, acc[r].x);
                acc[r].y = fmaf(xq.x, w0.y, acc[r].y);
                acc[r].x = fmaf(xq.y, w1.x, acc[r].x);
                acc[r].y = fmaf(xq.y, w1.y, acc[r].y);
                acc[r].x = fmaf(xq.z, w2.x, acc[r].x);
                acc[r].y = fmaf(xq.z, w2.y, acc[r].y);
                acc[r].x = fmaf(xq.w, w3.x, acc[r].x);
                acc[r].y = fmaf(xq.w, w3.y, acc[r].y);
            }
        }
        // ---- lorentz epilogue per row ----
        #pragma unroll
        for (int r = 0; r < RPW; ++r) {
            int row = row0 + r;
            float ax = acc[r].x + bv.x;
            float ay = acc[r].y + bv.y;
            float t0 = __shfl(ax, 0, 64);
            float ssq = waveReduceSum(ax * ax + ay * ay);
            float timev = sval / (1.f + expf(-t0)) + 1.5f;
            float sq = fmaxf(ssq - t0 * t0, EPSV);
            float fac = sqrtf(fmaxf((timev * timev - 1.f) / sq, EPSV));
            if (row < n) {
                float2 o;
                o.x = (lane == 0) ? timev : ax * fac;
                o.y = ay * fac;
                *(float2*)(out + (long)row * 128 + 2 * lane) = o;
            }
        }
    }
}

// ---------------- CSR gather (agg) ----------------

__global__ void gather_kernel(const float* __restrict__ X, const int* __restrict__ rs,
                              const int* __restrict__ ecol_s, const float* __restrict__ ew_s,
                              float* __restrict__ S, int n)
{
    int wid = threadIdx.x >> 6, lane = threadIdx.x & 63;
    for (int row = blockIdx.x * 4 + wid; row < n; row += gridDim.x * 4) {
        int beg = rs[row], end = rs[row + 1];
        float2 acc = {0.f, 0.f};
        for (int base = beg; base < end; base += 64) {
            int idx = base + lane;
            int colv = (idx < end) ? ecol_s[idx] : 0;
            float wv = (idx < end) ? ew_s[idx] : 0.f;
            int cnt = min(64, end - base);
            for (int j = 0; j < cnt; ++j) {
                int c = __shfl(colv, j, 64);
                float wj = __shfl(wv, j, 64);
                float2 xv = *(const float2*)(X + (long)c * 128 + 2 * lane);
                acc.x = fmaf(wj, xv.x, acc.x);
                acc.y = fmaf(wj, xv.y, acc.y);
            }
        }
        *(float2*)(S + (long)row * 128 + 2 * lane) = acc;
    }
}

// agg2 + lorentz-normalize + sign-flip + logits, fused
__global__ void gather_logits_kernel(
    const float* __restrict__ X, const int* __restrict__ rs,
    const int* __restrict__ ecol_s, const float* __restrict__ ew_s,
    const float* __restrict__ cls, const float* __restrict__ cbias,
    float* __restrict__ outp, int n)
{
    __shared__ float clsS[NCLS * 129];
    __shared__ float cbS[NCLS];
    __shared__ float xsrow[4][128];
    int tid = threadIdx.x;
    for (int idx = tid; idx < NCLS * 128; idx += 256) {
        int c = idx >> 7, k = idx & 127;
        clsS[c * 129 + k] = cls[idx];
    }
    if (tid < NCLS) cbS[tid] = cbias[tid];
    __syncthreads();
    int wid = tid >> 6, lane = tid & 63;
    float* xs = xsrow[wid];
    for (int row = blockIdx.x * 4 + wid; row < n; row += gridDim.x * 4) {
        int beg = rs[row], end = rs[row + 1];
        float2 acc = {0.f, 0.f};
        for (int base = beg; base < end; base += 64) {
            int idx = base + lane;
            int colv = (idx < end) ? ecol_s[idx] : 0;
            float wv = (idx < end) ? ew_s[idx] : 0.f;
            int cnt = min(64, end - base);
            for (int j = 0; j < cnt; ++j) {
                int c = __shfl(colv, j, 64);
                float wj = __shfl(wv, j, 64);
                float2 xv = *(const float2*)(X + (long)c * 128 + 2 * lane);
                acc.x = fmaf(wj, xv.x, acc.x);
                acc.y = fmaf(wj, xv.y, acc.y);
            }
        }
        float t0 = __shfl(acc.x, 0, 64);
        float ss = waveReduceSum(acc.x * acc.x + acc.y * acc.y);
        float neg_inner = 2.f * t0 * t0 - ss;
        float inv = 1.f / sqrtf(fmaxf(fabsf(neg_inner), EPSV));
        float2 xv;
        xv.x = acc.x * inv;
        xv.y = acc.y * inv;
        if (lane == 0) xv.x = -xv.x;
        xs[2 * lane] = xv.x;
        xs[2 * lane + 1] = xv.y;
        if (lane < NCLS) {
            float dot = 0.f;
            #pragma unroll 8
            for (int k = 0; k < 128; ++k)
                dot = fmaf(xs[k], clsS[lane * 129 + k], dot);
            outp[(long)row * NCLS + lane] = 2.f + 2.f * dot + cbS[lane];
        }
    }
}

// ---------------- launch ----------------

extern "C" void kernel_launch(void* const* d_in, const int* in_sizes, int n_in,
                              void* d_out, int out_size, void* d_ws, size_t ws_size,
                              hipStream_t stream) {
    const float* node_feat = (const float*)d_in[0];
    const float* W1   = (const float*)d_in[1];
    const float* b1   = (const float*)d_in[2];
    const float* s1   = (const float*)d_in[3];
    const float* W2   = (const float*)d_in[4];
    const float* b2   = (const float*)d_in[5];
    const float* s2   = (const float*)d_in[6];
    const float* cls  = (const float*)d_in[7];
    const float* cb   = (const float*)d_in[8];
    const float* ew   = (const float*)d_in[9];
    const int*   erow = (const int*)d_in[10];
    const int*   ecol = (const int*)d_in[11];
    float* outp = (float*)d_out;

    const int n = NN;
    const int E = in_sizes[9];
    const int NBLK = (NN + 255) / 256;   // 196

    float* bufA   = (float*)d_ws;                       // NN*128
    float* bufB   = bufA + (size_t)NN * 128;            // NN*128
    int*   rs     = (int*)(bufB + (size_t)NN * 128);    // NN+1
    int*   pos    = rs + (NN + 1);                      // NN
    int*   bsum   = pos + NN;                           // <=256
    int*   ecol_s = bsum + 256;                         // E
    float* ew_s   = (float*)(ecol_s + E);               // E

    // CSR build
    hipMemsetAsync(pos, 0, (size_t)NN * sizeof(int), stream);
    hist_kernel<<<2048, 256, 0, stream>>>(erow, pos, E);
    scan1_kernel<<<NBLK, 256, 0, stream>>>(pos, rs, bsum, n);
    scan2_kernel<<<1, 256, 0, stream>>>(bsum, NBLK);
    scan3_kernel<<<NBLK, 256, 0, stream>>>(rs, bsum, n, E);
    hipMemcpyAsync(pos, rs, (size_t)NN * sizeof(int), hipMemcpyDeviceToDevice, stream);
    fill_kernel<<<2048, 256, 0, stream>>>(erow, ecol, ew, pos, ecol_s, ew_s, E);

    // pipeline
    linear_lorentz<1><<<782, 256, 0, stream>>>(node_feat, W1, b1, s1, bufA, n);  // expmap+L1
    gather_kernel<<<4096, 256, 0, stream>>>(bufA, rs, ecol_s, ew_s, bufB, n);    // agg1
    linear_lorentz<0><<<782, 256, 0, stream>>>(bufB, W2, b2, s2, bufA, n);       // norm+relu+L2
    gather_logits_kernel<<<4096, 256, 0, stream>>>(bufA, rs, ecol_s, ew_s, cls, cb, outp, n); // agg2+logits
}

// Round 5
// 427.567 us; speedup vs baseline: 1.0605x; 1.0605x over previous
//
#include <hip/hip_runtime.h>
#include <math.h>

#define NN 50000
#define DD 128
#define NCLS 40
#define EPSV 1e-8f

__device__ __forceinline__ float waveReduceSum(float v) {
    for (int off = 32; off > 0; off >>= 1) v += __shfl_xor(v, off, 64);
    return v;
}

// ---------------- CSR build ----------------

__global__ void hist_kernel(const int* __restrict__ erow, int* __restrict__ cnt, int E) {
    for (int e = blockIdx.x * blockDim.x + threadIdx.x; e < E; e += gridDim.x * blockDim.x)
        atomicAdd(&cnt[erow[e]], 1);
}

__global__ void scan1_kernel(const int* __restrict__ cnt, int* __restrict__ rs,
                             int* __restrict__ bsum, int n) {
    __shared__ int sdata[256];
    int tid = threadIdx.x;
    int gid = blockIdx.x * 256 + tid;
    int v = (gid < n) ? cnt[gid] : 0;
    sdata[tid] = v;
    __syncthreads();
    for (int off = 1; off < 256; off <<= 1) {
        int t = (tid >= off) ? sdata[tid - off] : 0;
        __syncthreads();
        sdata[tid] += t;
        __syncthreads();
    }
    if (gid < n) rs[gid] = sdata[tid] - v;
    if (tid == 255) bsum[blockIdx.x] = sdata[255];
}

__global__ void scan2_kernel(int* __restrict__ bsum, int nb) {
    __shared__ int sdata[256];
    int tid = threadIdx.x;
    int v = (tid < nb) ? bsum[tid] : 0;
    sdata[tid] = v;
    __syncthreads();
    for (int off = 1; off < 256; off <<= 1) {
        int t = (tid >= off) ? sdata[tid - off] : 0;
        __syncthreads();
        sdata[tid] += t;
        __syncthreads();
    }
    if (tid < nb) bsum[tid] = sdata[tid] - v;
}

__global__ void scan3_kernel(int* __restrict__ rs, const int* __restrict__ bsum, int n, int E) {
    int gid = blockIdx.x * 256 + threadIdx.x;
    if (gid < n) rs[gid] += bsum[blockIdx.x];
    else if (gid == n) rs[n] = E;
}

__global__ void fill_kernel(const int* __restrict__ erow, const int* __restrict__ ecol,
                            const float* __restrict__ ew, int* __restrict__ pos,
                            int* __restrict__ ecol_s, float* __restrict__ ew_s, int E) {
    for (int e = blockIdx.x * blockDim.x + threadIdx.x; e < E; e += gridDim.x * blockDim.x) {
        int r = erow[e];
        int p = atomicAdd(&pos[r], 1);
        ecol_s[p] = ecol[e];
        ew_s[p] = ew[e];
    }
}

// ---------------- fused linears (8 rows per wave, W from global/L1) ----------------
// Lane l computes output cols 2l,2l+1 -> needs W rows 2l,2l+1 (contiguous, L1-hot).
// LDS holds only the preprocessed x slab (broadcast b128 reads, conflict-free).
// PREEXP=1: X is node_feat (N,127); apply expmap0 first.
// PREEXP=0: X is (N,128) raw agg sums; lorentz-normalize + relu first.
#define RPW 8
template <int PREEXP>
__global__ __launch_bounds__(512, 4) void linear_lorentz(
    const float* __restrict__ X, const float* __restrict__ W,
    const float* __restrict__ bias, const float* __restrict__ logs,
    float* __restrict__ out, int n)
{
    __shared__ float xrow[8][RPW * 128];     // 8 waves * 4KB = 32KB
    int tid = threadIdx.x;
    int wid = tid >> 6, lane = tid & 63;
    float2 bv = *(const float2*)(bias + 2 * lane);
    float sval = fminf(expf(logs[0]), 10.f);
    const float* wrow0 = W + (long)(2 * lane) * 128;       // row 2l
    const float* wrow1 = W + (long)(2 * lane + 1) * 128;   // row 2l+1
    float* xbase = xrow[wid];                              // wave-private
    int nslabs = (n + RPW - 1) / RPW;
    for (int slab = blockIdx.x * 8 + wid; slab < nslabs; slab += gridDim.x * 8) {
        int row0 = slab * RPW;
        // ---- preprocess RPW rows into LDS ----
        #pragma unroll
        for (int r = 0; r < RPW; ++r) {
            int row = row0 + r;
            if (row >= n) {
                *(float2*)(xbase + r * 128 + 2 * lane) = make_float2(0.f, 0.f);
                continue;
            }
            if (PREEXP) {
                const float* src = X + (long)row * 127;
                float u0 = src[2 * lane];
                float u1 = (2 * lane + 1 < 127) ? src[2 * lane + 1] : 0.f;
                float ss = waveReduceSum(u0 * u0 + u1 * u1);
                float nrm = fmaxf(sqrtf(ss), EPSV);
                float ex = expf(nrm), exn = 1.f / ex;
                float ch = 0.5f * (ex + exn);
                float coef = (0.5f * (ex - exn)) / nrm;
                if (lane == 0) xbase[r * 128] = ch;
                xbase[r * 128 + 1 + 2 * lane] = coef * u0;
                if (2 * lane + 1 < 127) xbase[r * 128 + 2 + 2 * lane] = coef * u1;
            } else {
                float2 e = *(const float2*)(X + (long)row * 128 + 2 * lane);
                float t0 = __shfl(e.x, 0, 64);
                float ss = waveReduceSum(e.x * e.x + e.y * e.y);
                float neg_inner = 2.f * t0 * t0 - ss;
                float inv = 1.f / sqrtf(fmaxf(fabsf(neg_inner), EPSV));
                e.x = fmaxf(e.x * inv, 0.f);
                e.y = fmaxf(e.y * inv, 0.f);
                *(float2*)(xbase + r * 128 + 2 * lane) = e;
            }
        }
        // xrow is wave-private: within-wave lgkmcnt ordering, no barrier needed
        // ---- GEMM: RPW rows x 128 cols; W rows stream from L1 ----
        float2 acc[RPW];
        #pragma unroll
        for (int r = 0; r < RPW; ++r) acc[r] = make_float2(0.f, 0.f);
        #pragma unroll 4
        for (int k0 = 0; k0 < 128; k0 += 4) {
            float4 wa = *(const float4*)(wrow0 + k0);
            float4 wb = *(const float4*)(wrow1 + k0);
            #pragma unroll
            for (int r = 0; r < RPW; ++r) {
                float4 xq = *(const float4*)(xbase + r * 128 + k0);  // LDS broadcast
                acc[r].x = fmaf(xq.x, wa.x, acc[r].x);
                acc[r].y = fmaf(xq.x, wb.x, acc[r].y);
                acc[r].x = fmaf(xq.y, wa.y, acc[r].x);
                acc[r].y = fmaf(xq.y, wb.y, acc[r].y);
                acc[r].x = fmaf(xq.z, wa.z, acc[r].x);
                acc[r].y = fmaf(xq.z, wb.z, acc[r].y);
                acc[r].x = fmaf(xq.w, wa.w, acc[r].x);
                acc[r].y = fmaf(xq.w, wb.w, acc[r].y);
            }
        }
        // ---- lorentz epilogue per row ----
        #pragma unroll
        for (int r = 0; r < RPW; ++r) {
            int row = row0 + r;
            float ax = acc[r].x + bv.x;
            float ay = acc[r].y + bv.y;
            float t0 = __shfl(ax, 0, 64);
            float ssq = waveReduceSum(ax * ax + ay * ay);
            float timev = sval / (1.f + expf(-t0)) + 1.5f;
            float sq = fmaxf(ssq - t0 * t0, EPSV);
            float fac = sqrtf(fmaxf((timev * timev - 1.f) / sq, EPSV));
            if (row < n) {
                float2 o;
                o.x = (lane == 0) ? timev : ax * fac;
                o.y = ay * fac;
                *(float2*)(out + (long)row * 128 + 2 * lane) = o;
            }
        }
    }
}

// ---------------- CSR gather (agg) ----------------

__global__ void gather_kernel(const float* __restrict__ X, const int* __restrict__ rs,
                              const int* __restrict__ ecol_s, const float* __restrict__ ew_s,
                              float* __restrict__ S, int n)
{
    int wid = threadIdx.x >> 6, lane = threadIdx.x & 63;
    for (int row = blockIdx.x * 4 + wid; row < n; row += gridDim.x * 4) {
        int beg = rs[row], end = rs[row + 1];
        float2 acc = {0.f, 0.f};
        for (int base = beg; base < end; base += 64) {
            int idx = base + lane;
            int colv = (idx < end) ? ecol_s[idx] : 0;
            float wv = (idx < end) ? ew_s[idx] : 0.f;
            int cnt = min(64, end - base);
            for (int j = 0; j < cnt; ++j) {
                int c = __shfl(colv, j, 64);
                float wj = __shfl(wv, j, 64);
                float2 xv = *(const float2*)(X + (long)c * 128 + 2 * lane);
                acc.x = fmaf(wj, xv.x, acc.x);
                acc.y = fmaf(wj, xv.y, acc.y);
            }
        }
        *(float2*)(S + (long)row * 128 + 2 * lane) = acc;
    }
}

// agg2 + lorentz-normalize + sign-flip + logits, fused
__global__ void gather_logits_kernel(
    const float* __restrict__ X, const int* __restrict__ rs,
    const int* __restrict__ ecol_s, const float* __restrict__ ew_s,
    const float* __restrict__ cls, const float* __restrict__ cbias,
    float* __restrict__ outp, int n)
{
    __shared__ float clsS[NCLS * 129];
    __shared__ float cbS[NCLS];
    __shared__ float xsrow[4][128];
    int tid = threadIdx.x;
    for (int idx = tid; idx < NCLS * 128; idx += 256) {
        int c = idx >> 7, k = idx & 127;
        clsS[c * 129 + k] = cls[idx];
    }
    if (tid < NCLS) cbS[tid] = cbias[tid];
    __syncthreads();
    int wid = tid >> 6, lane = tid & 63;
    float* xs = xsrow[wid];
    for (int row = blockIdx.x * 4 + wid; row < n; row += gridDim.x * 4) {
        int beg = rs[row], end = rs[row + 1];
        float2 acc = {0.f, 0.f};
        for (int base = beg; base < end; base += 64) {
            int idx = base + lane;
            int colv = (idx < end) ? ecol_s[idx] : 0;
            float wv = (idx < end) ? ew_s[idx] : 0.f;
            int cnt = min(64, end - base);
            for (int j = 0; j < cnt; ++j) {
                int c = __shfl(colv, j, 64);
                float wj = __shfl(wv, j, 64);
                float2 xv = *(const float2*)(X + (long)c * 128 + 2 * lane);
                acc.x = fmaf(wj, xv.x, acc.x);
                acc.y = fmaf(wj, xv.y, acc.y);
            }
        }
        float t0 = __shfl(acc.x, 0, 64);
        float ss = waveReduceSum(acc.x * acc.x + acc.y * acc.y);
        float neg_inner = 2.f * t0 * t0 - ss;
        float inv = 1.f / sqrtf(fmaxf(fabsf(neg_inner), EPSV));
        float2 xv;
        xv.x = acc.x * inv;
        xv.y = acc.y * inv;
        if (lane == 0) xv.x = -xv.x;
        xs[2 * lane] = xv.x;
        xs[2 * lane + 1] = xv.y;
        if (lane < NCLS) {
            float dot = 0.f;
            #pragma unroll 8
            for (int k = 0; k < 128; ++k)
                dot = fmaf(xs[k], clsS[lane * 129 + k], dot);
            outp[(long)row * NCLS + lane] = 2.f + 2.f * dot + cbS[lane];
        }
    }
}

// ---------------- launch ----------------

extern "C" void kernel_launch(void* const* d_in, const int* in_sizes, int n_in,
                              void* d_out, int out_size, void* d_ws, size_t ws_size,
                              hipStream_t stream) {
    const float* node_feat = (const float*)d_in[0];
    const float* W1   = (const float*)d_in[1];
    const float* b1   = (const float*)d_in[2];
    const float* s1   = (const float*)d_in[3];
    const float* W2   = (const float*)d_in[4];
    const float* b2   = (const float*)d_in[5];
    const float* s2   = (const float*)d_in[6];
    const float* cls  = (const float*)d_in[7];
    const float* cb   = (const float*)d_in[8];
    const float* ew   = (const float*)d_in[9];
    const int*   erow = (const int*)d_in[10];
    const int*   ecol = (const int*)d_in[11];
    float* outp = (float*)d_out;

    const int n = NN;
    const int E = in_sizes[9];
    const int NBLK = (NN + 255) / 256;   // 196

    float* bufA   = (float*)d_ws;                       // NN*128
    float* bufB   = bufA + (size_t)NN * 128;            // NN*128
    int*   rs     = (int*)(bufB + (size_t)NN * 128);    // NN+1
    int*   pos    = rs + (NN + 1);                      // NN
    int*   bsum   = pos + NN;                           // <=256
    int*   ecol_s = bsum + 256;                         // E
    float* ew_s   = (float*)(ecol_s + E);               // E

    // CSR build
    (void)hipMemsetAsync(pos, 0, (size_t)NN * sizeof(int), stream);
    hist_kernel<<<2048, 256, 0, stream>>>(erow, pos, E);
    scan1_kernel<<<NBLK, 256, 0, stream>>>(pos, rs, bsum, n);
    scan2_kernel<<<1, 256, 0, stream>>>(bsum, NBLK);
    scan3_kernel<<<NBLK, 256, 0, stream>>>(rs, bsum, n, E);
    (void)hipMemcpyAsync(pos, rs, (size_t)NN * sizeof(int), hipMemcpyDeviceToDevice, stream);
    fill_kernel<<<2048, 256, 0, stream>>>(erow, ecol, ew, pos, ecol_s, ew_s, E);

    // pipeline
    linear_lorentz<1><<<512, 512, 0, stream>>>(node_feat, W1, b1, s1, bufA, n);  // expmap+L1
    gather_kernel<<<4096, 256, 0, stream>>>(bufA, rs, ecol_s, ew_s, bufB, n);    // agg1
    linear_lorentz<0><<<512, 512, 0, stream>>>(bufB, W2, b2, s2, bufA, n);       // norm+relu+L2
    gather_logits_kernel<<<4096, 256, 0, stream>>>(bufA, rs, ecol_s, ew_s, cls, cb, outp, n); // agg2+logits
}

// Round 6
// 417.578 us; speedup vs baseline: 1.0858x; 1.0239x over previous
//
#include <hip/hip_runtime.h>
#include <math.h>

#define NN 50000
#define DD 128
#define NCLS 40
#define EPSV 1e-8f

__device__ __forceinline__ float waveReduceSum(float v) {
    for (int off = 32; off > 0; off >>= 1) v += __shfl_xor(v, off, 64);
    return v;
}

// ---------------- CSR build ----------------

__global__ void hist_kernel(const int* __restrict__ erow, int* __restrict__ cnt, int E) {
    for (int e = blockIdx.x * blockDim.x + threadIdx.x; e < E; e += gridDim.x * blockDim.x)
        atomicAdd(&cnt[erow[e]], 1);
}

__global__ void scan1_kernel(const int* __restrict__ cnt, int* __restrict__ rs,
                             int* __restrict__ bsum, int n) {
    __shared__ int sdata[256];
    int tid = threadIdx.x;
    int gid = blockIdx.x * 256 + tid;
    int v = (gid < n) ? cnt[gid] : 0;
    sdata[tid] = v;
    __syncthreads();
    for (int off = 1; off < 256; off <<= 1) {
        int t = (tid >= off) ? sdata[tid - off] : 0;
        __syncthreads();
        sdata[tid] += t;
        __syncthreads();
    }
    if (gid < n) rs[gid] = sdata[tid] - v;
    if (tid == 255) bsum[blockIdx.x] = sdata[255];
}

__global__ void scan2_kernel(int* __restrict__ bsum, int nb) {
    __shared__ int sdata[256];
    int tid = threadIdx.x;
    int v = (tid < nb) ? bsum[tid] : 0;
    sdata[tid] = v;
    __syncthreads();
    for (int off = 1; off < 256; off <<= 1) {
        int t = (tid >= off) ? sdata[tid - off] : 0;
        __syncthreads();
        sdata[tid] += t;
        __syncthreads();
    }
    if (tid < nb) bsum[tid] = sdata[tid] - v;
}

__global__ void scan3_kernel(int* __restrict__ rs, const int* __restrict__ bsum, int n, int E) {
    int gid = blockIdx.x * 256 + threadIdx.x;
    if (gid < n) rs[gid] += bsum[blockIdx.x];
    else if (gid == n) rs[n] = E;
}

__global__ void fill_kernel(const int* __restrict__ erow, const int* __restrict__ ecol,
                            const float* __restrict__ ew, int* __restrict__ pos,
                            int* __restrict__ ecol_s, float* __restrict__ ew_s, int E) {
    for (int e = blockIdx.x * blockDim.x + threadIdx.x; e < E; e += gridDim.x * blockDim.x) {
        int r = erow[e];
        int p = atomicAdd(&pos[r], 1);
        ecol_s[p] = ecol[e];
        ew_s[p] = ew[e];
    }
}

// ---------------- fused linears ----------------
// 8 rows/wave. W transposed in LDS (staged conflict-free: lane-consecutive words;
// row reads are 128 consecutive words = conflict-free). x slab per wave in LDS,
// read via uniform-address b128 broadcast (free). 96KB LDS -> 1 block(8 waves)/CU.
// PREEXP=1: X is node_feat (N,127); apply expmap0 first.
// PREEXP=0: X is (N,128) raw agg sums; lorentz-normalize + relu first.
#define RPW 8
template <int PREEXP>
__global__ __launch_bounds__(512) void linear_lorentz(
    const float* __restrict__ X, const float* __restrict__ W,
    const float* __restrict__ bias, const float* __restrict__ logs,
    float* __restrict__ out, int n)
{
    __shared__ float Wt[128 * 128];          // Wt[k*128+i] = W[i*128+k]  (64 KB)
    __shared__ float xrow[8][RPW * 128];     // 8 waves * 4KB = 32KB -> 96KB total
    int tid = threadIdx.x;
    int wid = tid >> 6, lane = tid & 63;
    // stage W transposed: lanes write consecutive words -> conflict-free
    for (int idx = tid; idx < 128 * 128; idx += 512) {
        int i = idx >> 7, k = idx & 127;     // read W row-major (coalesced)
        Wt[k * 128 + i] = W[idx];
    }
    __syncthreads();
    float2 bv = *(const float2*)(bias + 2 * lane);
    float sval = fminf(expf(logs[0]), 10.f);
    float* xbase = xrow[wid];                // wave-private
    int nslabs = (n + RPW - 1) / RPW;
    for (int slab = blockIdx.x * 8 + wid; slab < nslabs; slab += gridDim.x * 8) {
        int row0 = slab * RPW;
        // ---- preprocess RPW rows into LDS ----
        #pragma unroll
        for (int r = 0; r < RPW; ++r) {
            int row = row0 + r;
            if (row >= n) {
                *(float2*)(xbase + r * 128 + 2 * lane) = make_float2(0.f, 0.f);
                continue;
            }
            if (PREEXP) {
                const float* src = X + (long)row * 127;
                float u0 = src[2 * lane];
                float u1 = (2 * lane + 1 < 127) ? src[2 * lane + 1] : 0.f;
                float ss = waveReduceSum(u0 * u0 + u1 * u1);
                float nrm = fmaxf(sqrtf(ss), EPSV);
                float ex = expf(nrm), exn = 1.f / ex;
                float ch = 0.5f * (ex + exn);
                float coef = (0.5f * (ex - exn)) / nrm;
                if (lane == 0) xbase[r * 128] = ch;
                xbase[r * 128 + 1 + 2 * lane] = coef * u0;
                if (2 * lane + 1 < 127) xbase[r * 128 + 2 + 2 * lane] = coef * u1;
            } else {
                float2 e = *(const float2*)(X + (long)row * 128 + 2 * lane);
                float t0 = __shfl(e.x, 0, 64);
                float ss = waveReduceSum(e.x * e.x + e.y * e.y);
                float neg_inner = 2.f * t0 * t0 - ss;
                float inv = 1.f / sqrtf(fmaxf(fabsf(neg_inner), EPSV));
                e.x = fmaxf(e.x * inv, 0.f);
                e.y = fmaxf(e.y * inv, 0.f);
                *(float2*)(xbase + r * 128 + 2 * lane) = e;
            }
        }
        // xrow wave-private: within-wave lgkmcnt ordering, no barrier needed
        // ---- GEMM: RPW rows x 128 cols; W rows from LDS (conflict-free) ----
        float2 acc[RPW];
        #pragma unroll
        for (int r = 0; r < RPW; ++r) acc[r] = make_float2(0.f, 0.f);
        #pragma unroll 4
        for (int k0 = 0; k0 < 128; k0 += 4) {
            float2 w0 = *(const float2*)(Wt + (k0 + 0) * 128 + 2 * lane);
            float2 w1 = *(const float2*)(Wt + (k0 + 1) * 128 + 2 * lane);
            float2 w2 = *(const float2*)(Wt + (k0 + 2) * 128 + 2 * lane);
            float2 w3 = *(const float2*)(Wt + (k0 + 3) * 128 + 2 * lane);
            #pragma unroll
            for (int r = 0; r < RPW; ++r) {
                float4 xq = *(const float4*)(xbase + r * 128 + k0);  // LDS broadcast
                acc[r].x = fmaf(xq.x, w0.x, acc[r].x);
                acc[r].y = fmaf(xq.x, w0.y, acc[r].y);
                acc[r].x = fmaf(xq.y, w1.x, acc[r].x);
                acc[r].y = fmaf(xq.y, w1.y, acc[r].y);
                acc[r].x = fmaf(xq.z, w2.x, acc[r].x);
                acc[r].y = fmaf(xq.z, w2.y, acc[r].y);
                acc[r].x = fmaf(xq.w, w3.x, acc[r].x);
                acc[r].y = fmaf(xq.w, w3.y, acc[r].y);
            }
        }
        // ---- lorentz epilogue per row ----
        #pragma unroll
        for (int r = 0; r < RPW; ++r) {
            int row = row0 + r;
            float ax = acc[r].x + bv.x;
            float ay = acc[r].y + bv.y;
            float t0 = __shfl(ax, 0, 64);
            float ssq = waveReduceSum(ax * ax + ay * ay);
            float timev = sval / (1.f + expf(-t0)) + 1.5f;
            float sq = fmaxf(ssq - t0 * t0, EPSV);
            float fac = sqrtf(fmaxf((timev * timev - 1.f) / sq, EPSV));
            if (row < n) {
                float2 o;
                o.x = (lane == 0) ? timev : ax * fac;
                o.y = ay * fac;
                *(float2*)(out + (long)row * 128 + 2 * lane) = o;
            }
        }
    }
}

// ---------------- CSR gather (agg) ----------------

__global__ void gather_kernel(const float* __restrict__ X, const int* __restrict__ rs,
                              const int* __restrict__ ecol_s, const float* __restrict__ ew_s,
                              float* __restrict__ S, int n)
{
    int wid = threadIdx.x >> 6, lane = threadIdx.x & 63;
    for (int row = blockIdx.x * 4 + wid; row < n; row += gridDim.x * 4) {
        int beg = rs[row], end = rs[row + 1];
        float2 acc = {0.f, 0.f};
        for (int base = beg; base < end; base += 64) {
            int idx = base + lane;
            int colv = (idx < end) ? ecol_s[idx] : 0;
            float wv = (idx < end) ? ew_s[idx] : 0.f;
            int cnt = min(64, end - base);
            for (int j = 0; j < cnt; ++j) {
                int c = __shfl(colv, j, 64);
                float wj = __shfl(wv, j, 64);
                float2 xv = *(const float2*)(X + (long)c * 128 + 2 * lane);
                acc.x = fmaf(wj, xv.x, acc.x);
                acc.y = fmaf(wj, xv.y, acc.y);
            }
        }
        *(float2*)(S + (long)row * 128 + 2 * lane) = acc;
    }
}

// agg2 + lorentz-normalize + sign-flip + logits, fused
__global__ void gather_logits_kernel(
    const float* __restrict__ X, const int* __restrict__ rs,
    const int* __restrict__ ecol_s, const float* __restrict__ ew_s,
    const float* __restrict__ cls, const float* __restrict__ cbias,
    float* __restrict__ outp, int n)
{
    __shared__ float clsS[NCLS * 129];
    __shared__ float cbS[NCLS];
    __shared__ float xsrow[4][128];
    int tid = threadIdx.x;
    for (int idx = tid; idx < NCLS * 128; idx += 256) {
        int c = idx >> 7, k = idx & 127;
        clsS[c * 129 + k] = cls[idx];
    }
    if (tid < NCLS) cbS[tid] = cbias[tid];
    __syncthreads();
    int wid = tid >> 6, lane = tid & 63;
    float* xs = xsrow[wid];
    for (int row = blockIdx.x * 4 + wid; row < n; row += gridDim.x * 4) {
        int beg = rs[row], end = rs[row + 1];
        float2 acc = {0.f, 0.f};
        for (int base = beg; base < end; base += 64) {
            int idx = base + lane;
            int colv = (idx < end) ? ecol_s[idx] : 0;
            float wv = (idx < end) ? ew_s[idx] : 0.f;
            int cnt = min(64, end - base);
            for (int j = 0; j < cnt; ++j) {
                int c = __shfl(colv, j, 64);
                float wj = __shfl(wv, j, 64);
                float2 xv = *(const float2*)(X + (long)c * 128 + 2 * lane);
                acc.x = fmaf(wj, xv.x, acc.x);
                acc.y = fmaf(wj, xv.y, acc.y);
            }
        }
        float t0 = __shfl(acc.x, 0, 64);
        float ss = waveReduceSum(acc.x * acc.x + acc.y * acc.y);
        float neg_inner = 2.f * t0 * t0 - ss;
        float inv = 1.f / sqrtf(fmaxf(fabsf(neg_inner), EPSV));
        float2 xv;
        xv.x = acc.x * inv;
        xv.y = acc.y * inv;
        if (lane == 0) xv.x = -xv.x;
        xs[2 * lane] = xv.x;
        xs[2 * lane + 1] = xv.y;
        if (lane < NCLS) {
            float dot = 0.f;
            #pragma unroll 8
            for (int k = 0; k < 128; ++k)
                dot = fmaf(xs[k], clsS[lane * 129 + k], dot);
            outp[(long)row * NCLS + lane] = 2.f + 2.f * dot + cbS[lane];
        }
    }
}

// ---------------- launch ----------------

extern "C" void kernel_launch(void* const* d_in, const int* in_sizes, int n_in,
                              void* d_out, int out_size, void* d_ws, size_t ws_size,
                              hipStream_t stream) {
    const float* node_feat = (const float*)d_in[0];
    const float* W1   = (const float*)d_in[1];
    const float* b1   = (const float*)d_in[2];
    const float* s1   = (const float*)d_in[3];
    const float* W2   = (const float*)d_in[4];
    const float* b2   = (const float*)d_in[5];
    const float* s2   = (const float*)d_in[6];
    const float* cls  = (const float*)d_in[7];
    const float* cb   = (const float*)d_in[8];
    const float* ew   = (const float*)d_in[9];
    const int*   erow = (const int*)d_in[10];
    const int*   ecol = (const int*)d_in[11];
    float* outp = (float*)d_out;

    const int n = NN;
    const int E = in_sizes[9];
    const int NBLK = (NN + 255) / 256;   // 196

    float* bufA   = (float*)d_ws;                       // NN*128
    float* bufB   = bufA + (size_t)NN * 128;            // NN*128
    int*   rs     = (int*)(bufB + (size_t)NN * 128);    // NN+1
    int*   pos    = rs + (NN + 1);                      // NN
    int*   bsum   = pos + NN;                           // <=256
    int*   ecol_s = bsum + 256;                         // E
    float* ew_s   = (float*)(ecol_s + E);               // E

    // CSR build
    (void)hipMemsetAsync(pos, 0, (size_t)NN * sizeof(int), stream);
    hist_kernel<<<2048, 256, 0, stream>>>(erow, pos, E);
    scan1_kernel<<<NBLK, 256, 0, stream>>>(pos, rs, bsum, n);
    scan2_kernel<<<1, 256, 0, stream>>>(bsum, NBLK);
    scan3_kernel<<<NBLK, 256, 0, stream>>>(rs, bsum, n, E);
    (void)hipMemcpyAsync(pos, rs, (size_t)NN * sizeof(int), hipMemcpyDeviceToDevice, stream);
    fill_kernel<<<2048, 256, 0, stream>>>(erow, ecol, ew, pos, ecol_s, ew_s, E);

    // pipeline
    linear_lorentz<1><<<256, 512, 0, stream>>>(node_feat, W1, b1, s1, bufA, n);  // expmap+L1
    gather_kernel<<<4096, 256, 0, stream>>>(bufA, rs, ecol_s, ew_s, bufB, n);    // agg1
    linear_lorentz<0><<<256, 512, 0, stream>>>(bufB, W2, b2, s2, bufA, n);       // norm+relu+L2
    gather_logits_kernel<<<4096, 256, 0, stream>>>(bufA, rs, ecol_s, ew_s, cls, cb, outp, n); // agg2+logits
}